// Round 16
// baseline (300.796 us; speedup 1.0000x reference)
//
#include <hip/hip_runtime.h>
#include <stdint.h>

#define NS 64      // samples
#define NA 256     // assets
#define NC 8       // clusters
#define NI 10      // inits
#define MAXIT 30   // lloyd iterations
#define MSMALL 64  // small-solve path bound
#define MLDS 132   // large-solve LDS bound (140 KB)

typedef unsigned int u32;
typedef unsigned long long u64;

struct Key { u32 x, y; };

// Threefry-2x32, 20 rounds — exact JAX semantics.
__device__ __forceinline__ void tf2x32(u32 k0, u32 k1, u32 c0, u32 c1, u32& o0, u32& o1) {
  u32 ks0 = k0, ks1 = k1, ks2 = k0 ^ k1 ^ 0x1BD11BDAu;
  u32 x0 = c0 + ks0, x1 = c1 + ks1;
#define TFR(r) { x0 += x1; x1 = (x1 << (r)) | (x1 >> (32 - (r))); x1 ^= x0; }
  TFR(13) TFR(15) TFR(26) TFR(6)
  x0 += ks1; x1 += ks2 + 1u;
  TFR(17) TFR(29) TFR(16) TFR(24)
  x0 += ks2; x1 += ks0 + 2u;
  TFR(13) TFR(15) TFR(26) TFR(6)
  x0 += ks0; x1 += ks1 + 3u;
  TFR(17) TFR(29) TFR(16) TFR(24)
  x0 += ks1; x1 += ks2 + 4u;
  TFR(13) TFR(15) TFR(26) TFR(6)
  x0 += ks2; x1 += ks0 + 5u;
#undef TFR
  o0 = x0; o1 = x1;
}

// jax_threefry_partitionable=True semantics (verified round 2):
__device__ __forceinline__ Key key_row(Key k, u32 j) {
  Key r; tf2x32(k.x, k.y, 0u, j, r.x, r.y); return r;
}
__device__ __forceinline__ u32 rbits32(Key k, u32 i) {
  u32 o0, o1; tf2x32(k.x, k.y, 0u, i, o0, o1); return o0 ^ o1;
}

// ---------------- Gram G = corr * corr^T (f64), triangle-only, fused diag ------------
__global__ __launch_bounds__(256) void nco_gram_kernel(
    const float* __restrict__ cov, double* __restrict__ G) {
  int b = blockIdx.x;                 // j*10 + tile
  int j = b / 10, tile = b - 10 * j;
  const int TIa[10] = {0,0,0,0,1,1,1,2,2,3};
  const int TJa[10] = {0,1,2,3,1,2,3,2,3,3};
  int ti2 = TIa[tile], tj2 = TJa[tile];
  const float* C = cov + (size_t)j * NA * NA;
  double* Gj = G + (size_t)j * NA * NA;

  __shared__ double sinv[NA];
  __shared__ double As[16][64 + 1];   // As[kk][row]
  __shared__ double Bs[16][64 + 1];
  int t = threadIdx.x;
  int tr = t >> 4, tc = t & 15;       // 16x16 thread tile, each 4x4 out

  sinv[t] = 1.0 / sqrt((double)C[(size_t)t * NA + t]);
  __syncthreads();

  double acc[4][4];
#pragma unroll
  for (int a = 0; a < 4; a++)
#pragma unroll
    for (int bb = 0; bb < 4; bb++) acc[a][bb] = 0.0;

  for (int k0 = 0; k0 < NA; k0 += 16) {
    int kk = t & 15, rr = t >> 4;
    double ck = sinv[k0 + kk];
#pragma unroll
    for (int m = 0; m < 4; m++) {
      int r = rr + 16 * m;
      int gr = ti2 * 64 + r;
      As[kk][r] = (double)C[(size_t)gr * NA + k0 + kk] * sinv[gr] * ck;
      int gc = tj2 * 64 + r;
      Bs[kk][r] = (double)C[(size_t)gc * NA + k0 + kk] * sinv[gc] * ck;
    }
    __syncthreads();
#pragma unroll
    for (int kk2 = 0; kk2 < 16; kk2++) {
      double ar[4], br[4];
#pragma unroll
      for (int m = 0; m < 4; m++) ar[m] = As[kk2][tr + 16 * m];
#pragma unroll
      for (int m = 0; m < 4; m++) br[m] = Bs[kk2][tc + 16 * m];
#pragma unroll
      for (int a = 0; a < 4; a++)
#pragma unroll
        for (int bb = 0; bb < 4; bb++) acc[a][bb] = fma(ar[a], br[bb], acc[a][bb]);
    }
    __syncthreads();
  }
#pragma unroll
  for (int a = 0; a < 4; a++) {
    int gr = ti2 * 64 + tr + 16 * a;
#pragma unroll
    for (int bb = 0; bb < 4; bb++) {
      int gc = tj2 * 64 + tc + 16 * bb;
      Gj[(size_t)gr * NA + gc] = acc[a][bb];
      if (ti2 != tj2) Gj[(size_t)gc * NA + gr] = acc[a][bb];  // symmetry mirror
    }
  }
}

// ---------------- k-means (incremental Gram sums via ballot diffs) -------------------
// Round-16: 4-way batched bit extraction in the diff loops. Loads for up to 4
// extracted rows issue together (invalid slots re-load p0 -> always in-bounds);
// accumulation stays in ascending order, guarded -> BIT-EXACT vs round 11,
// ~4x fewer load-latency stalls (the it=1 sweep was a 220cy/row serial chain).
__global__ __launch_bounds__(512) void nco_kmeans_kernel(
    const double* __restrict__ G, int* __restrict__ ixsAll,
    double* __restrict__ inertiaAll) {
  int b = blockIdx.x;                 // 0..639
  int xcd = b & 7, s0 = b >> 3;
  int j  = xcd + 8 * (s0 / NI);       // sample (bijective XCD swizzle)
  int mi = s0 - (s0 / NI) * NI;       // init
  int blk = j * NI + mi;
  int tid = threadIdx.x;
  int t = tid & 255;                  // point / column
  int g = tid >> 8;                   // group 0..1
  int w4 = tid >> 6;                  // wave id (group0 waves: 0..3)
  const double* Gj = G + (size_t)j * NA * NA;

  __shared__ int    li[NC][NA];       // 8 KiB member lists
  __shared__ double sv[NC][NA];       // 16 KiB s_k[t] (persistent)
  __shared__ int    wcnt[4][NC];
  __shared__ u64    balPrev[4][NC];   // ballots of CURRENT list contents
  __shared__ u64    balNew[4][NC];
  __shared__ u64    dAdd[4][NC];      // diff masks (valid when dirty)
  __shared__ u64    dRem[4][NC];
  __shared__ int    nsz[NC];
  __shared__ int    dirty[NC];
  __shared__ double part[NC][8];
  __shared__ double sinvn[NC], ck2[NC];  // persistent across iters
  __shared__ u32    bits[NA];

  if (g == 0) {
    Key base; base.x = 0u; base.y = 42u;        // jax.random.key(42)
    Key skey = key_row(base, (u32)j);           // split(base, 64)[j]
    Key ikey = key_row(skey, (u32)mi);          // split(skey, 10)[mi]
    Key sub  = key_row(ikey, 1u);               // _shuffle subkey
    bits[t] = rbits32(sub, (u32)t);
  }
  __syncthreads();
  if (g == 0) {
    u32 mine = bits[t];
    int rank = 0;
    for (int u = 0; u < NA; u++) {
      u32 b2 = bits[u];
      rank += (b2 < mine) || (b2 == mine && u < t);
    }
    if (rank < NC) li[rank][0] = t;
    if (t < NC) { nsz[t] = 1; dirty[t] = 1; }
#pragma unroll
    for (int k = 0; k < NC; k++) {                // seed balPrev = singleton ballots
      u64 bal = __ballot(rank == k);
      if ((t & 63) == 0) balPrev[w4][k] = bal;
    }
  }
  __syncthreads();

  double xx = (g == 0) ? Gj[(size_t)t * NA + t] : 0.0;  // ||x_t||^2 (inertia only)
  int myix = -1;
  double fb = 0.0;
  for (int it = 0; it <= MAXIT; ++it) {
    if (it > 0) {
      u64 mybal = 0;
      if (g == 0) {
#pragma unroll
        for (int k = 0; k < NC; k++) {
          u64 bal = __ballot(myix == k);
          if ((t & 63) == 0) { wcnt[w4][k] = (int)__popcll(bal); balNew[w4][k] = bal; }
          if (k == myix) mybal = bal;
        }
      }
      __syncthreads();                 // (A)
      if (g == 0) {
        if (t < NC) {
          int tot = wcnt[0][t] + wcnt[1][t] + wcnt[2][t] + wcnt[3][t];
          if (tot > 0) {
            nsz[t] = tot;
            bool d = (balNew[0][t] != balPrev[0][t]) | (balNew[1][t] != balPrev[1][t]) |
                     (balNew[2][t] != balPrev[2][t]) | (balNew[3][t] != balPrev[3][t]);
            dirty[t] = d ? 1 : 0;
            if (d) {
#pragma unroll
              for (int w2 = 0; w2 < 4; w2++) {
                dAdd[w2][t] = balNew[w2][t] & ~balPrev[w2][t];
                dRem[w2][t] = balPrev[w2][t] & ~balNew[w2][t];
                balPrev[w2][t] = balNew[w2][t];
              }
            }
          } else {
            dirty[t] = 0;              // empty -> frozen list/size/sums (balPrev kept)
          }
        }
        int k = myix;                  // my cluster is non-empty (contains me)
        int base = 0;
        for (int w2 = 0; w2 < w4; w2++) base += wcnt[w2][k];
        li[k][base + (int)__popcll(mybal & ((1ULL << (t & 63)) - 1ULL))] = t;
      }
      __syncthreads();                 // (B)
      if (!(dirty[0] | dirty[1] | dirty[2] | dirty[3] |
            dirty[4] | dirty[5] | dirty[6] | dirty[7])) break;

      for (int k = g; k < NC; k += 2) {
        if (!dirty[k]) continue;
        double acc = sv[k][t];
        // ---- removals: 4-way batched extraction, in-order subtract ----
#pragma unroll
        for (int wq = 0; wq < 4; wq++) {
          u64 m0 = dRem[wq][k];
          while (m0) {
            int p0 = (wq << 6) + (int)__builtin_ctzll(m0); m0 &= m0 - 1;
            int p1 = p0, p2 = p0, p3 = p0, nvalid = 1;
            if (m0) { p1 = (wq << 6) + (int)__builtin_ctzll(m0); m0 &= m0 - 1; nvalid = 2; }
            if (m0) { p2 = (wq << 6) + (int)__builtin_ctzll(m0); m0 &= m0 - 1; nvalid = 3; }
            if (m0) { p3 = (wq << 6) + (int)__builtin_ctzll(m0); m0 &= m0 - 1; nvalid = 4; }
            double g0 = Gj[(size_t)p0 * NA + t];
            double g1 = Gj[(size_t)p1 * NA + t];
            double g2 = Gj[(size_t)p2 * NA + t];
            double g3 = Gj[(size_t)p3 * NA + t];
            acc -= g0;
            if (nvalid > 1) acc -= g1;
            if (nvalid > 2) acc -= g2;
            if (nvalid > 3) acc -= g3;
          }
        }
        // ---- additions: 4-way batched extraction, in-order add ----
#pragma unroll
        for (int wq = 0; wq < 4; wq++) {
          u64 m0 = dAdd[wq][k];
          while (m0) {
            int p0 = (wq << 6) + (int)__builtin_ctzll(m0); m0 &= m0 - 1;
            int p1 = p0, p2 = p0, p3 = p0, nvalid = 1;
            if (m0) { p1 = (wq << 6) + (int)__builtin_ctzll(m0); m0 &= m0 - 1; nvalid = 2; }
            if (m0) { p2 = (wq << 6) + (int)__builtin_ctzll(m0); m0 &= m0 - 1; nvalid = 3; }
            if (m0) { p3 = (wq << 6) + (int)__builtin_ctzll(m0); m0 &= m0 - 1; nvalid = 4; }
            double g0 = Gj[(size_t)p0 * NA + t];
            double g1 = Gj[(size_t)p1 * NA + t];
            double g2 = Gj[(size_t)p2 * NA + t];
            double g3 = Gj[(size_t)p3 * NA + t];
            acc += g0;
            if (nvalid > 1) acc += g1;
            if (nvalid > 2) acc += g2;
            if (nvalid > 3) acc += g3;
          }
        }
        sv[k][t] = acc;
      }
    } else {
      for (int k = g; k < NC; k += 2) {
        int p = li[k][0];
        sv[k][t] = Gj[(size_t)p * NA + t];
      }
    }
    __syncthreads();                   // (C)

    if (tid < 64) {
      int k = tid >> 3, r = tid & 7;
      if (dirty[k]) {
        int n = nsz[k];
        double p = 0.0;
        for (int i = r; i < n; i += 8) p += sv[k][li[k][i]];
        part[k][r] = p;
      }
      __builtin_amdgcn_wave_barrier();
      if (tid < NC && dirty[tid]) {
        double S = 0.0;
#pragma unroll
        for (int r2 = 0; r2 < 8; r2++) S += part[tid][r2];
        double inn = 1.0 / (double)nsz[tid];
        sinvn[tid] = inn;
        ck2[tid] = S * inn * inn;
      }
    }
    __syncthreads();                   // (F)

    if (g == 0) {
      double best = ck2[0] - 2.0 * sv[0][t] * sinvn[0]; int bi = 0;
#pragma unroll
      for (int k = 1; k < NC; k++) {
        double f = ck2[k] - 2.0 * sv[k][t] * sinvn[k];
        if (f < best) { best = f; bi = k; }   // first-min = jnp.argmin
      }
      fb = best;
      myix = bi;
    }
    // no barrier: next iteration's (A)+(B) fence sv reuse before any rewrite
  }

  __syncthreads();
  double* red = (double*)&li[0][0];    // li dead after loop; reuse as scratch
  if (g == 0) red[t] = xx + fb;        // min d^2 of point t
  __syncthreads();
  if (g == 0) ixsAll[blk * NA + t] = myix;
  if (tid == 0) {
    double ss = 0.0;
    for (int i = 0; i < NA; i++) ss += red[i];   // exact i-order
    inertiaAll[blk] = ss;
  }
}

// ---------------- csolve SMALL (m <= 64): single-wave, pivot-row cached --------------
__global__ __launch_bounds__(256) void nco_csolve_small(
    const float* __restrict__ cov, const float* __restrict__ rets,
    const int* __restrict__ ixsAll, const double* __restrict__ inertiaAll,
    double* __restrict__ wc_all) {
  int b = blockIdx.x;                 // j*NC + c
  int j = b >> 3, c = b & 7;
  int t = threadIdx.x, w = t >> 6;
  const float* C = cov + (size_t)j * NA * NA;
  const float* r = rets + (size_t)j * NA;

  __shared__ double bufl[MSMALL * (MSMALL + 1)];  // 33.3 KiB
  __shared__ double prow[MSMALL];                 // pivot-row cache (distinct object)
  __shared__ int    li[NA];
  __shared__ int    wcnt[4][NC];
  __shared__ int    scnt[NC];
  __shared__ int    sbest;
  __shared__ double rhs[NA];
  __shared__ double wsub[NA];

  if (t == 0) {
    double bv = inertiaAll[j * NI]; int bb = 0;
    for (int m = 1; m < NI; m++) {
      double v = inertiaAll[j * NI + m];
      if (v < bv) { bv = v; bb = m; }             // first-min
    }
    sbest = bb;
  }
  __syncthreads();
  const int* ixs = ixsAll + (size_t)(j * NI + sbest) * NA;

  int myc = ixs[t];
  u64 mybal = 0;
#pragma unroll
  for (int u = 0; u < NC; u++) {
    u64 bal = __ballot(myc == u);
    if ((t & 63) == 0) wcnt[w][u] = (int)__popcll(bal);
    if (u == myc) mybal = bal;
  }
  __syncthreads();
  if (t < NC) scnt[t] = wcnt[0][t] + wcnt[1][t] + wcnt[2][t] + wcnt[3][t];
  __syncthreads();
  if (myc == c) {
    int base = 0;
    for (int w2 = 0; w2 < w; w2++) base += wcnt[w2][c];
    li[base + (int)__popcll(mybal & ((1ULL << (t & 63)) - 1ULL))] = t;
  }
  __syncthreads();

  int m = scnt[c];
  if (m > MSMALL) return;              // large kernel owns this column

  double* wcc = wc_all + ((size_t)j * NC + c) * NA;
  wcc[t] = 0.0;                        // this kernel owns the column now
  if (m == 0) return;

  int ms = m | 1;                      // odd stride
  for (int idx = t; idx < m * m; idx += NA) {
    int row = idx / m, col = idx - row * m;
    bufl[row * ms + col] = (double)C[(size_t)li[row] * NA + li[col]];
  }
  if (t < m) rhs[t] = (double)r[li[t]];
  __syncthreads();
  if (t < 64) {
    for (int k = 0; k < m - 1; k++) {
      for (int q = k + 1 + t; q < m; q += 64) prow[q] = bufl[k * ms + q];
      __builtin_amdgcn_wave_barrier();
      double piv = bufl[k * ms + k];
      if (t > k && t < m) {
        double f = bufl[t * ms + k] / piv;
        rhs[t] -= f * rhs[k];
        for (int b2 = k + 1; b2 < m; b2++)
          bufl[t * ms + b2] -= f * prow[b2];     // read prow, write bufl: pipelined
      }
      __builtin_amdgcn_wave_barrier();
    }
    for (int a = m - 1; a >= 0; a--) {
      if (t == a) wsub[a] = rhs[a] / bufl[a * ms + a];
      __builtin_amdgcn_wave_barrier();
      if (t < a) rhs[t] -= bufl[t * ms + a] * wsub[a];
      __builtin_amdgcn_wave_barrier();
    }
    double ssum = 0.0;                 // redundant per-lane sum (no sync needed)
    for (int a = 0; a < m; a++) ssum += wsub[a];
    if (t < m) wcc[li[t]] = (ssum != 0.0) ? (wsub[t] / ssum) : 0.0;
  }
}

// ---------------- csolve LARGE (64 < m): 512 threads, pivot-row cached ---------------
__global__ __launch_bounds__(512) void nco_csolve_large(
    const float* __restrict__ cov, const float* __restrict__ rets,
    const int* __restrict__ ixsAll, const double* __restrict__ inertiaAll,
    double* __restrict__ gbuf_all, double* __restrict__ wc_all) {
  int b = blockIdx.x;                 // j*NC + c
  int j = b >> 3, c = b & 7;
  int tid = threadIdx.x;
  int t = tid & 255, w = t >> 6;      // preamble roles for tid < 256
  const float* C = cov + (size_t)j * NA * NA;
  const float* r = rets + (size_t)j * NA;

  __shared__ double bufl[MLDS * (MLDS + 1)];      // 140.4 KiB
  __shared__ double prowL[NA];                    // pivot-row cache (distinct object)
  __shared__ int    li[NA];
  __shared__ int    wcnt[4][NC];
  __shared__ int    scnt[NC];
  __shared__ int    sbest;
  __shared__ double rhs[NA];
  __shared__ double wsub[NA];
  __shared__ double fv[NA];

  if (tid == 0) {
    double bv = inertiaAll[j * NI]; int bb = 0;
    for (int m = 1; m < NI; m++) {
      double v = inertiaAll[j * NI + m];
      if (v < bv) { bv = v; bb = m; }             // first-min
    }
    sbest = bb;
  }
  __syncthreads();
  const int* ixs = ixsAll + (size_t)(j * NI + sbest) * NA;

  int myc = (tid < 256) ? ixs[t] : -1;
  u64 mybal = 0;
#pragma unroll
  for (int u = 0; u < NC; u++) {
    u64 bal = __ballot(myc == u);
    if (tid < 256 && (t & 63) == 0) wcnt[w][u] = (int)__popcll(bal);
    if (u == myc) mybal = bal;
  }
  __syncthreads();
  if (tid < NC) scnt[tid] = wcnt[0][tid] + wcnt[1][tid] + wcnt[2][tid] + wcnt[3][tid];
  __syncthreads();
  if (tid < 256 && myc == c) {
    int base = 0;
    for (int w2 = 0; w2 < w; w2++) base += wcnt[w2][c];
    li[base + (int)__popcll(mybal & ((1ULL << (t & 63)) - 1ULL))] = t;
  }
  __syncthreads();

  int m = scnt[c];
  if (m <= MSMALL) return;             // small kernel owns this column

  double* wcc = wc_all + ((size_t)j * NC + c) * NA;
  if (tid < 256) wcc[tid] = 0.0;       // this kernel owns the column now

  int inlds = (m <= MLDS);
  int msl = inlds ? (m | 1) : m;       // odd stride in LDS; natural in global
  double* bp = inlds ? bufl : ({
    int soff = 0;
    for (int u = 0; u < c; u++) soff += scnt[u] * scnt[u];
    gbuf_all + (size_t)j * NA * NA + soff; });

  for (int idx = tid; idx < m * m; idx += 512) {
    int row = idx / m, col = idx - row * m;
    bp[(size_t)row * msl + col] = (double)C[(size_t)li[row] * NA + li[col]];
  }
  if (tid < m) rhs[tid] = (double)r[li[tid]];
  __syncthreads();

  for (int k = 0; k < m - 1; k++) {
    double piv = bp[(size_t)k * msl + k];
    int nr = m - 1 - k;                // active rows k+1..m-1
    if (tid < nr) {
      int row = k + 1 + tid;
      double f = bp[(size_t)row * msl + k] / piv;
      fv[row] = f;
      rhs[row] -= f * rhs[k];
    }
    for (int q = k + 1 + tid; q < m; q += 512) prowL[q] = bp[(size_t)k * msl + q];
    __syncthreads();
    int tot = nr * nr;
    for (int idx = tid; idx < tot; idx += 512) {
      int rr = idx / nr, cc = idx - rr * nr;
      int row = k + 1 + rr, col = k + 1 + cc;
      bp[(size_t)row * msl + col] -= fv[row] * prowL[col];   // pipelined
    }
    __syncthreads();
  }

  // single-wave back-substitution (lane owns rows tid, tid+64, ...)
  if (tid < 64) {
    for (int a = m - 1; a >= 0; a--) {
      if ((a & 63) == tid) wsub[a] = rhs[a] / bp[(size_t)a * msl + a];
      __builtin_amdgcn_wave_barrier();
      for (int r2 = tid; r2 < a; r2 += 64) rhs[r2] -= bp[(size_t)r2 * msl + a] * wsub[a];
      __builtin_amdgcn_wave_barrier();
    }
    double ssum = 0.0;                 // redundant per-lane sum
    for (int a = 0; a < m; a++) ssum += wsub[a];
    for (int r2 = tid; r2 < m; r2 += 64)
      wcc[li[r2]] = (ssum != 0.0) ? (wsub[r2] / ssum) : 0.0;
  }
}

// ---------------- per-sample inter-cluster assembly + output ----------------
__global__ __launch_bounds__(256) void nco_inter_kernel(
    const float* __restrict__ cov, const float* __restrict__ rets,
    const double* __restrict__ wc_all, float* __restrict__ out) {
  int j = blockIdx.x, t = threadIdx.x;
  const float* C = cov + (size_t)j * NA * NA;
  const float* r = rets + (size_t)j * NA;

  __shared__ double wc[NC][NA];
  __shared__ double tmpL[NC][NA];
  __shared__ double interA[NC][NC];
  __shared__ double interb[NC];
  __shared__ double wi[NC];

  for (int c = 0; c < NC; c++) wc[c][t] = wc_all[((size_t)j * NC + c) * NA + t];
  __syncthreads();

  {
    double tcol[NC];
#pragma unroll
    for (int c = 0; c < NC; c++) tcol[c] = 0.0;
    for (int p = 0; p < NA; p++) {
      double cv = (double)C[(size_t)p * NA + t];
#pragma unroll
      for (int c = 0; c < NC; c++) tcol[c] += wc[c][p] * cv;
    }
#pragma unroll
    for (int c = 0; c < NC; c++) tmpL[c][t] = tcol[c];
  }
  __syncthreads();

  if (t < NC * NC) {
    int c = t / NC, c2 = t % NC;
    double s = 0.0;
    for (int q = 0; q < NA; q++) s += tmpL[c][q] * wc[c2][q];
    interA[c][c2] = s;
  }
  if (t >= 64 && t < 64 + NC) {
    int c = t - 64;
    double s = 0.0;
    for (int p = 0; p < NA; p++) s += wc[c][p] * (double)r[p];
    interb[c] = s;
  }
  __syncthreads();

  if (t == 0) {
    double A[NC][NC], bb[NC];
    for (int a = 0; a < NC; a++) {
      bb[a] = interb[a];
      for (int q = 0; q < NC; q++) A[a][q] = interA[a][q];
    }
    for (int k = 0; k < NC; k++) {
      int p = k; double mx = fabs(A[k][k]);
      for (int i2 = k + 1; i2 < NC; i2++) {
        double v = fabs(A[i2][k]);
        if (v > mx) { mx = v; p = i2; }
      }
      if (p != k) {
        for (int q = 0; q < NC; q++) { double tv = A[k][q]; A[k][q] = A[p][q]; A[p][q] = tv; }
        double tb = bb[k]; bb[k] = bb[p]; bb[p] = tb;
      }
      for (int i2 = k + 1; i2 < NC; i2++) {
        double f = A[i2][k] / A[k][k];
        bb[i2] -= f * bb[k];
        for (int q = k + 1; q < NC; q++) A[i2][q] -= f * A[k][q];
      }
    }
    double w[NC];
    for (int a = NC - 1; a >= 0; a--) {
      double s = bb[a];
      for (int q = a + 1; q < NC; q++) s -= A[a][q] * w[q];
      w[a] = s / A[a][a];
    }
    double ssum = 0.0;
    for (int a = 0; a < NC; a++) ssum += w[a];
    for (int a = 0; a < NC; a++) wi[a] = w[a] / ssum;
  }
  __syncthreads();

  double o = 0.0;
#pragma unroll
  for (int c = 0; c < NC; c++) o += wc[c][t] * wi[c];
  out[(size_t)j * NA + t] = (float)o;
}

extern "C" void kernel_launch(void* const* d_in, const int* in_sizes, int n_in,
                              void* d_out, int out_size, void* d_ws, size_t ws_size,
                              hipStream_t stream) {
  const float* cov  = (const float*)d_in[0];
  const float* rets = (const float*)d_in[1];
  float* out = (float*)d_out;
  char* ws = (char*)d_ws;

  const size_t g_bytes = (size_t)NS * NA * NA * sizeof(double);        // 32 MiB
  double* G          = (double*)(ws);
  double* inertiaAll = (double*)(ws + g_bytes);                        // 5 KiB
  int*    ixsAll     = (int*)   (ws + g_bytes + 5120);                 // 640 KiB
  double* wc_all     = (double*)(ws + g_bytes + 5120 + 655360);        // 1 MiB
  double* gbuf_all   = G;       // alias: G dead after kmeans

  hipLaunchKernelGGL(nco_gram_kernel,   dim3(NS * 10), dim3(NA),  0, stream, cov, G);
  hipLaunchKernelGGL(nco_kmeans_kernel, dim3(NS * NI), dim3(512), 0, stream,
                     G, ixsAll, inertiaAll);
  hipLaunchKernelGGL(nco_csolve_small,  dim3(NS * NC), dim3(NA),  0, stream,
                     cov, rets, ixsAll, inertiaAll, wc_all);
  hipLaunchKernelGGL(nco_csolve_large,  dim3(NS * NC), dim3(512), 0, stream,
                     cov, rets, ixsAll, inertiaAll, gbuf_all, wc_all);
  hipLaunchKernelGGL(nco_inter_kernel,  dim3(NS),      dim3(NA),  0, stream,
                     cov, rets, wc_all, out);
}

// Round 17
// 275.253 us; speedup vs baseline: 1.0928x; 1.0928x over previous
//
#include <hip/hip_runtime.h>
#include <stdint.h>

#define NS 64      // samples
#define NA 256     // assets
#define NC 8       // clusters
#define NI 10      // inits
#define MAXIT 30   // lloyd iterations
#define MSMALL 64  // small-solve path bound
#define MLDS 132   // large-solve LDS bound (140 KB)

typedef unsigned int u32;
typedef unsigned long long u64;

struct Key { u32 x, y; };

// Threefry-2x32, 20 rounds — exact JAX semantics.
__device__ __forceinline__ void tf2x32(u32 k0, u32 k1, u32 c0, u32 c1, u32& o0, u32& o1) {
  u32 ks0 = k0, ks1 = k1, ks2 = k0 ^ k1 ^ 0x1BD11BDAu;
  u32 x0 = c0 + ks0, x1 = c1 + ks1;
#define TFR(r) { x0 += x1; x1 = (x1 << (r)) | (x1 >> (32 - (r))); x1 ^= x0; }
  TFR(13) TFR(15) TFR(26) TFR(6)
  x0 += ks1; x1 += ks2 + 1u;
  TFR(17) TFR(29) TFR(16) TFR(24)
  x0 += ks2; x1 += ks0 + 2u;
  TFR(13) TFR(15) TFR(26) TFR(6)
  x0 += ks0; x1 += ks1 + 3u;
  TFR(17) TFR(29) TFR(16) TFR(24)
  x0 += ks1; x1 += ks2 + 4u;
  TFR(13) TFR(15) TFR(26) TFR(6)
  x0 += ks2; x1 += ks0 + 5u;
#undef TFR
  o0 = x0; o1 = x1;
}

// jax_threefry_partitionable=True semantics (verified round 2):
__device__ __forceinline__ Key key_row(Key k, u32 j) {
  Key r; tf2x32(k.x, k.y, 0u, j, r.x, r.y); return r;
}
__device__ __forceinline__ u32 rbits32(Key k, u32 i) {
  u32 o0, o1; tf2x32(k.x, k.y, 0u, i, o0, o1); return o0 ^ o1;
}

// ---------------- Gram G = corr * corr^T (f64), triangle-only, fused diag ------------
__global__ __launch_bounds__(256) void nco_gram_kernel(
    const float* __restrict__ cov, double* __restrict__ G) {
  int b = blockIdx.x;                 // j*10 + tile
  int j = b / 10, tile = b - 10 * j;
  const int TIa[10] = {0,0,0,0,1,1,1,2,2,3};
  const int TJa[10] = {0,1,2,3,1,2,3,2,3,3};
  int ti2 = TIa[tile], tj2 = TJa[tile];
  const float* C = cov + (size_t)j * NA * NA;
  double* Gj = G + (size_t)j * NA * NA;

  __shared__ double sinv[NA];
  __shared__ double As[16][64 + 1];   // As[kk][row]
  __shared__ double Bs[16][64 + 1];
  int t = threadIdx.x;
  int tr = t >> 4, tc = t & 15;       // 16x16 thread tile, each 4x4 out

  sinv[t] = 1.0 / sqrt((double)C[(size_t)t * NA + t]);
  __syncthreads();

  double acc[4][4];
#pragma unroll
  for (int a = 0; a < 4; a++)
#pragma unroll
    for (int bb = 0; bb < 4; bb++) acc[a][bb] = 0.0;

  for (int k0 = 0; k0 < NA; k0 += 16) {
    int kk = t & 15, rr = t >> 4;
    double ck = sinv[k0 + kk];
#pragma unroll
    for (int m = 0; m < 4; m++) {
      int r = rr + 16 * m;
      int gr = ti2 * 64 + r;
      As[kk][r] = (double)C[(size_t)gr * NA + k0 + kk] * sinv[gr] * ck;
      int gc = tj2 * 64 + r;
      Bs[kk][r] = (double)C[(size_t)gc * NA + k0 + kk] * sinv[gc] * ck;
    }
    __syncthreads();
#pragma unroll
    for (int kk2 = 0; kk2 < 16; kk2++) {
      double ar[4], br[4];
#pragma unroll
      for (int m = 0; m < 4; m++) ar[m] = As[kk2][tr + 16 * m];
#pragma unroll
      for (int m = 0; m < 4; m++) br[m] = Bs[kk2][tc + 16 * m];
#pragma unroll
      for (int a = 0; a < 4; a++)
#pragma unroll
        for (int bb = 0; bb < 4; bb++) acc[a][bb] = fma(ar[a], br[bb], acc[a][bb]);
    }
    __syncthreads();
  }
#pragma unroll
  for (int a = 0; a < 4; a++) {
    int gr = ti2 * 64 + tr + 16 * a;
#pragma unroll
    for (int bb = 0; bb < 4; bb++) {
      int gc = tj2 * 64 + tc + 16 * bb;
      Gj[(size_t)gr * NA + gc] = acc[a][bb];
      if (ti2 != tj2) Gj[(size_t)gc * NA + gr] = acc[a][bb];  // symmetry mirror
    }
  }
}

// ---------------- k-means (incremental Gram sums via ballot diffs) -------------------
// Round-17: round-15 verified structure; at it==1 dirty clusters use the
// round-8 4-wide-unrolled fresh list sweep (independent a0..a3 accumulators
// pipeline the L2 loads) instead of the serial singleton-diff chain. Reorder
// class ~1e-15, same as the accepted round-8 -> round-11 switch. it>=2 keeps
// the verified serial incremental path (diffs are small there).
__global__ __launch_bounds__(512) void nco_kmeans_kernel(
    const double* __restrict__ G, int* __restrict__ ixsAll,
    double* __restrict__ inertiaAll) {
  int b = blockIdx.x;                 // 0..639
  int xcd = b & 7, s0 = b >> 3;
  int j  = xcd + 8 * (s0 / NI);       // sample (bijective XCD swizzle)
  int mi = s0 - (s0 / NI) * NI;       // init
  int blk = j * NI + mi;
  int tid = threadIdx.x;
  int t = tid & 255;                  // point / column
  int g = tid >> 8;                   // group 0..1
  int w4 = tid >> 6;                  // wave id (group0 waves: 0..3)
  const double* Gj = G + (size_t)j * NA * NA;

  __shared__ int    li[NC][NA];       // 8 KiB member lists
  __shared__ double sv[NC][NA];       // 16 KiB s_k[t] (persistent)
  __shared__ int    wcnt[4][NC];
  __shared__ u64    balPrev[4][NC];   // ballots of CURRENT list contents
  __shared__ u64    balNew[4][NC];
  __shared__ u64    dAdd[4][NC];      // diff masks (valid when dirty)
  __shared__ u64    dRem[4][NC];
  __shared__ int    nsz[NC];
  __shared__ int    dirty[NC];
  __shared__ double part[NC][8];
  __shared__ double sinvn[NC], ck2[NC];  // persistent across iters
  __shared__ u32    bits[NA];

  if (g == 0) {
    Key base; base.x = 0u; base.y = 42u;        // jax.random.key(42)
    Key skey = key_row(base, (u32)j);           // split(base, 64)[j]
    Key ikey = key_row(skey, (u32)mi);          // split(skey, 10)[mi]
    Key sub  = key_row(ikey, 1u);               // _shuffle subkey
    bits[t] = rbits32(sub, (u32)t);
  }
  __syncthreads();
  if (g == 0) {
    u32 mine = bits[t];
    int rank = 0;
    for (int u = 0; u < NA; u++) {
      u32 b2 = bits[u];
      rank += (b2 < mine) || (b2 == mine && u < t);
    }
    if (rank < NC) li[rank][0] = t;
    if (t < NC) { nsz[t] = 1; dirty[t] = 1; }
#pragma unroll
    for (int k = 0; k < NC; k++) {                // seed balPrev = singleton ballots
      u64 bal = __ballot(rank == k);
      if ((t & 63) == 0) balPrev[w4][k] = bal;
    }
  }
  __syncthreads();

  double xx = (g == 0) ? Gj[(size_t)t * NA + t] : 0.0;  // ||x_t||^2 (inertia only)
  int myix = -1;
  double fb = 0.0;
  for (int it = 0; it <= MAXIT; ++it) {
    if (it > 0) {
      u64 mybal = 0;
      if (g == 0) {
#pragma unroll
        for (int k = 0; k < NC; k++) {
          u64 bal = __ballot(myix == k);
          if ((t & 63) == 0) { wcnt[w4][k] = (int)__popcll(bal); balNew[w4][k] = bal; }
          if (k == myix) mybal = bal;
        }
      }
      __syncthreads();                 // (A)
      if (g == 0) {
        if (t < NC) {
          int tot = wcnt[0][t] + wcnt[1][t] + wcnt[2][t] + wcnt[3][t];
          if (tot > 0) {
            nsz[t] = tot;
            bool d = (balNew[0][t] != balPrev[0][t]) | (balNew[1][t] != balPrev[1][t]) |
                     (balNew[2][t] != balPrev[2][t]) | (balNew[3][t] != balPrev[3][t]);
            dirty[t] = d ? 1 : 0;
            if (d) {
#pragma unroll
              for (int w2 = 0; w2 < 4; w2++) {
                dAdd[w2][t] = balNew[w2][t] & ~balPrev[w2][t];
                dRem[w2][t] = balPrev[w2][t] & ~balNew[w2][t];
                balPrev[w2][t] = balNew[w2][t];
              }
            }
          } else {
            dirty[t] = 0;              // empty -> frozen list/size/sums (balPrev kept)
          }
        }
        int k = myix;                  // my cluster is non-empty (contains me)
        int base = 0;
        for (int w2 = 0; w2 < w4; w2++) base += wcnt[w2][k];
        li[k][base + (int)__popcll(mybal & ((1ULL << (t & 63)) - 1ULL))] = t;
      }
      __syncthreads();                 // (B)
      if (!(dirty[0] | dirty[1] | dirty[2] | dirty[3] |
            dirty[4] | dirty[5] | dirty[6] | dirty[7])) break;

      for (int k = g; k < NC; k += 2) {
        if (!dirty[k]) continue;
        if (it == 1) {
          // fresh 4-wide-unrolled list sweep (round-8 verified pattern):
          // independent a0..a3 let the loads pipeline 4-deep.
          int n = nsz[k];
          const int* lk = li[k];
          double a0 = 0.0, a1 = 0.0;
          int i = 0;
          for (; i + 4 <= n; i += 4) {
            int r0 = lk[i], r1 = lk[i + 1], r2 = lk[i + 2], r3 = lk[i + 3];
            double g0 = Gj[(size_t)r0 * NA + t];
            double g1 = Gj[(size_t)r1 * NA + t];
            double g2 = Gj[(size_t)r2 * NA + t];
            double g3 = Gj[(size_t)r3 * NA + t];
            a0 += g0; a1 += g1; a0 += g2; a1 += g3;
          }
          for (; i < n; ++i) a0 += Gj[(size_t)lk[i] * NA + t];
          sv[k][t] = a0 + a1;
        } else {
          double acc = sv[k][t];
#pragma unroll
          for (int wq = 0; wq < 4; wq++) {
            u64 m0 = dRem[wq][k];
            while (m0) {
              int p = (wq << 6) + (int)__builtin_ctzll(m0);
              m0 &= m0 - 1;
              acc -= Gj[(size_t)p * NA + t];
            }
          }
#pragma unroll
          for (int wq = 0; wq < 4; wq++) {
            u64 m0 = dAdd[wq][k];
            while (m0) {
              int p = (wq << 6) + (int)__builtin_ctzll(m0);
              m0 &= m0 - 1;
              acc += Gj[(size_t)p * NA + t];
            }
          }
          sv[k][t] = acc;
        }
      }
    } else {
      for (int k = g; k < NC; k += 2) {
        int p = li[k][0];
        sv[k][t] = Gj[(size_t)p * NA + t];
      }
    }
    __syncthreads();                   // (C)

    if (tid < 64) {
      int k = tid >> 3, r = tid & 7;
      if (dirty[k]) {
        int n = nsz[k];
        double p = 0.0;
        for (int i = r; i < n; i += 8) p += sv[k][li[k][i]];
        part[k][r] = p;
      }
      __builtin_amdgcn_wave_barrier();
      if (tid < NC && dirty[tid]) {
        double S = 0.0;
#pragma unroll
        for (int r2 = 0; r2 < 8; r2++) S += part[tid][r2];
        double inn = 1.0 / (double)nsz[tid];
        sinvn[tid] = inn;
        ck2[tid] = S * inn * inn;
      }
    }
    __syncthreads();                   // (F)

    if (g == 0) {
      double best = ck2[0] - 2.0 * sv[0][t] * sinvn[0]; int bi = 0;
#pragma unroll
      for (int k = 1; k < NC; k++) {
        double f = ck2[k] - 2.0 * sv[k][t] * sinvn[k];
        if (f < best) { best = f; bi = k; }   // first-min = jnp.argmin
      }
      fb = best;
      myix = bi;
    }
    // no barrier: next iteration's (A)+(B) fence sv reuse before any rewrite
  }

  __syncthreads();
  double* red = (double*)&li[0][0];    // li dead after loop; reuse as scratch
  if (g == 0) red[t] = xx + fb;        // min d^2 of point t
  __syncthreads();
  if (g == 0) ixsAll[blk * NA + t] = myix;
  if (tid == 0) {
    double ss = 0.0;
    for (int i = 0; i < NA; i++) ss += red[i];   // exact i-order
    inertiaAll[blk] = ss;
  }
}

// ---------------- csolve SMALL (m <= 64): single-wave, pivot-row cached --------------
__global__ __launch_bounds__(256) void nco_csolve_small(
    const float* __restrict__ cov, const float* __restrict__ rets,
    const int* __restrict__ ixsAll, const double* __restrict__ inertiaAll,
    double* __restrict__ wc_all) {
  int b = blockIdx.x;                 // j*NC + c
  int j = b >> 3, c = b & 7;
  int t = threadIdx.x, w = t >> 6;
  const float* C = cov + (size_t)j * NA * NA;
  const float* r = rets + (size_t)j * NA;

  __shared__ double bufl[MSMALL * (MSMALL + 1)];  // 33.3 KiB
  __shared__ double prow[MSMALL];                 // pivot-row cache (distinct object)
  __shared__ int    li[NA];
  __shared__ int    wcnt[4][NC];
  __shared__ int    scnt[NC];
  __shared__ int    sbest;
  __shared__ double rhs[NA];
  __shared__ double wsub[NA];

  if (t == 0) {
    double bv = inertiaAll[j * NI]; int bb = 0;
    for (int m = 1; m < NI; m++) {
      double v = inertiaAll[j * NI + m];
      if (v < bv) { bv = v; bb = m; }             // first-min
    }
    sbest = bb;
  }
  __syncthreads();
  const int* ixs = ixsAll + (size_t)(j * NI + sbest) * NA;

  int myc = ixs[t];
  u64 mybal = 0;
#pragma unroll
  for (int u = 0; u < NC; u++) {
    u64 bal = __ballot(myc == u);
    if ((t & 63) == 0) wcnt[w][u] = (int)__popcll(bal);
    if (u == myc) mybal = bal;
  }
  __syncthreads();
  if (t < NC) scnt[t] = wcnt[0][t] + wcnt[1][t] + wcnt[2][t] + wcnt[3][t];
  __syncthreads();
  if (myc == c) {
    int base = 0;
    for (int w2 = 0; w2 < w; w2++) base += wcnt[w2][c];
    li[base + (int)__popcll(mybal & ((1ULL << (t & 63)) - 1ULL))] = t;
  }
  __syncthreads();

  int m = scnt[c];
  if (m > MSMALL) return;              // large kernel owns this column

  double* wcc = wc_all + ((size_t)j * NC + c) * NA;
  wcc[t] = 0.0;                        // this kernel owns the column now
  if (m == 0) return;

  int ms = m | 1;                      // odd stride
  for (int idx = t; idx < m * m; idx += NA) {
    int row = idx / m, col = idx - row * m;
    bufl[row * ms + col] = (double)C[(size_t)li[row] * NA + li[col]];
  }
  if (t < m) rhs[t] = (double)r[li[t]];
  __syncthreads();
  if (t < 64) {
    for (int k = 0; k < m - 1; k++) {
      for (int q = k + 1 + t; q < m; q += 64) prow[q] = bufl[k * ms + q];
      __builtin_amdgcn_wave_barrier();
      double piv = bufl[k * ms + k];
      if (t > k && t < m) {
        double f = bufl[t * ms + k] / piv;
        rhs[t] -= f * rhs[k];
        for (int b2 = k + 1; b2 < m; b2++)
          bufl[t * ms + b2] -= f * prow[b2];     // read prow, write bufl: pipelined
      }
      __builtin_amdgcn_wave_barrier();
    }
    for (int a = m - 1; a >= 0; a--) {
      if (t == a) wsub[a] = rhs[a] / bufl[a * ms + a];
      __builtin_amdgcn_wave_barrier();
      if (t < a) rhs[t] -= bufl[t * ms + a] * wsub[a];
      __builtin_amdgcn_wave_barrier();
    }
    double ssum = 0.0;                 // redundant per-lane sum (no sync needed)
    for (int a = 0; a < m; a++) ssum += wsub[a];
    if (t < m) wcc[li[t]] = (ssum != 0.0) ? (wsub[t] / ssum) : 0.0;
  }
}

// ---------------- csolve LARGE (64 < m): 512 threads, pivot-row cached ---------------
__global__ __launch_bounds__(512) void nco_csolve_large(
    const float* __restrict__ cov, const float* __restrict__ rets,
    const int* __restrict__ ixsAll, const double* __restrict__ inertiaAll,
    double* __restrict__ gbuf_all, double* __restrict__ wc_all) {
  int b = blockIdx.x;                 // j*NC + c
  int j = b >> 3, c = b & 7;
  int tid = threadIdx.x;
  int t = tid & 255, w = t >> 6;      // preamble roles for tid < 256
  const float* C = cov + (size_t)j * NA * NA;
  const float* r = rets + (size_t)j * NA;

  __shared__ double bufl[MLDS * (MLDS + 1)];      // 140.4 KiB
  __shared__ double prowL[NA];                    // pivot-row cache (distinct object)
  __shared__ int    li[NA];
  __shared__ int    wcnt[4][NC];
  __shared__ int    scnt[NC];
  __shared__ int    sbest;
  __shared__ double rhs[NA];
  __shared__ double wsub[NA];
  __shared__ double fv[NA];

  if (tid == 0) {
    double bv = inertiaAll[j * NI]; int bb = 0;
    for (int m = 1; m < NI; m++) {
      double v = inertiaAll[j * NI + m];
      if (v < bv) { bv = v; bb = m; }             // first-min
    }
    sbest = bb;
  }
  __syncthreads();
  const int* ixs = ixsAll + (size_t)(j * NI + sbest) * NA;

  int myc = (tid < 256) ? ixs[t] : -1;
  u64 mybal = 0;
#pragma unroll
  for (int u = 0; u < NC; u++) {
    u64 bal = __ballot(myc == u);
    if (tid < 256 && (t & 63) == 0) wcnt[w][u] = (int)__popcll(bal);
    if (u == myc) mybal = bal;
  }
  __syncthreads();
  if (tid < NC) scnt[tid] = wcnt[0][tid] + wcnt[1][tid] + wcnt[2][tid] + wcnt[3][tid];
  __syncthreads();
  if (tid < 256 && myc == c) {
    int base = 0;
    for (int w2 = 0; w2 < w; w2++) base += wcnt[w2][c];
    li[base + (int)__popcll(mybal & ((1ULL << (t & 63)) - 1ULL))] = t;
  }
  __syncthreads();

  int m = scnt[c];
  if (m <= MSMALL) return;             // small kernel owns this column

  double* wcc = wc_all + ((size_t)j * NC + c) * NA;
  if (tid < 256) wcc[tid] = 0.0;       // this kernel owns the column now

  int inlds = (m <= MLDS);
  int msl = inlds ? (m | 1) : m;       // odd stride in LDS; natural in global
  double* bp = inlds ? bufl : ({
    int soff = 0;
    for (int u = 0; u < c; u++) soff += scnt[u] * scnt[u];
    gbuf_all + (size_t)j * NA * NA + soff; });

  for (int idx = tid; idx < m * m; idx += 512) {
    int row = idx / m, col = idx - row * m;
    bp[(size_t)row * msl + col] = (double)C[(size_t)li[row] * NA + li[col]];
  }
  if (tid < m) rhs[tid] = (double)r[li[tid]];
  __syncthreads();

  for (int k = 0; k < m - 1; k++) {
    double piv = bp[(size_t)k * msl + k];
    int nr = m - 1 - k;                // active rows k+1..m-1
    if (tid < nr) {
      int row = k + 1 + tid;
      double f = bp[(size_t)row * msl + k] / piv;
      fv[row] = f;
      rhs[row] -= f * rhs[k];
    }
    for (int q = k + 1 + tid; q < m; q += 512) prowL[q] = bp[(size_t)k * msl + q];
    __syncthreads();
    int tot = nr * nr;
    for (int idx = tid; idx < tot; idx += 512) {
      int rr = idx / nr, cc = idx - rr * nr;
      int row = k + 1 + rr, col = k + 1 + cc;
      bp[(size_t)row * msl + col] -= fv[row] * prowL[col];   // pipelined
    }
    __syncthreads();
  }

  // single-wave back-substitution (lane owns rows tid, tid+64, ...)
  if (tid < 64) {
    for (int a = m - 1; a >= 0; a--) {
      if ((a & 63) == tid) wsub[a] = rhs[a] / bp[(size_t)a * msl + a];
      __builtin_amdgcn_wave_barrier();
      for (int r2 = tid; r2 < a; r2 += 64) rhs[r2] -= bp[(size_t)r2 * msl + a] * wsub[a];
      __builtin_amdgcn_wave_barrier();
    }
    double ssum = 0.0;                 // redundant per-lane sum
    for (int a = 0; a < m; a++) ssum += wsub[a];
    for (int r2 = tid; r2 < m; r2 += 64)
      wcc[li[r2]] = (ssum != 0.0) ? (wsub[r2] / ssum) : 0.0;
  }
}

// ---------------- per-sample inter-cluster assembly + output ----------------
__global__ __launch_bounds__(256) void nco_inter_kernel(
    const float* __restrict__ cov, const float* __restrict__ rets,
    const double* __restrict__ wc_all, float* __restrict__ out) {
  int j = blockIdx.x, t = threadIdx.x;
  const float* C = cov + (size_t)j * NA * NA;
  const float* r = rets + (size_t)j * NA;

  __shared__ double wc[NC][NA];
  __shared__ double tmpL[NC][NA];
  __shared__ double interA[NC][NC];
  __shared__ double interb[NC];
  __shared__ double wi[NC];

  for (int c = 0; c < NC; c++) wc[c][t] = wc_all[((size_t)j * NC + c) * NA + t];
  __syncthreads();

  {
    double tcol[NC];
#pragma unroll
    for (int c = 0; c < NC; c++) tcol[c] = 0.0;
    for (int p = 0; p < NA; p++) {
      double cv = (double)C[(size_t)p * NA + t];
#pragma unroll
      for (int c = 0; c < NC; c++) tcol[c] += wc[c][p] * cv;
    }
#pragma unroll
    for (int c = 0; c < NC; c++) tmpL[c][t] = tcol[c];
  }
  __syncthreads();

  if (t < NC * NC) {
    int c = t / NC, c2 = t % NC;
    double s = 0.0;
    for (int q = 0; q < NA; q++) s += tmpL[c][q] * wc[c2][q];
    interA[c][c2] = s;
  }
  if (t >= 64 && t < 64 + NC) {
    int c = t - 64;
    double s = 0.0;
    for (int p = 0; p < NA; p++) s += wc[c][p] * (double)r[p];
    interb[c] = s;
  }
  __syncthreads();

  if (t == 0) {
    double A[NC][NC], bb[NC];
    for (int a = 0; a < NC; a++) {
      bb[a] = interb[a];
      for (int q = 0; q < NC; q++) A[a][q] = interA[a][q];
    }
    for (int k = 0; k < NC; k++) {
      int p = k; double mx = fabs(A[k][k]);
      for (int i2 = k + 1; i2 < NC; i2++) {
        double v = fabs(A[i2][k]);
        if (v > mx) { mx = v; p = i2; }
      }
      if (p != k) {
        for (int q = 0; q < NC; q++) { double tv = A[k][q]; A[k][q] = A[p][q]; A[p][q] = tv; }
        double tb = bb[k]; bb[k] = bb[p]; bb[p] = tb;
      }
      for (int i2 = k + 1; i2 < NC; i2++) {
        double f = A[i2][k] / A[k][k];
        bb[i2] -= f * bb[k];
        for (int q = k + 1; q < NC; q++) A[i2][q] -= f * A[k][q];
      }
    }
    double w[NC];
    for (int a = NC - 1; a >= 0; a--) {
      double s = bb[a];
      for (int q = a + 1; q < NC; q++) s -= A[a][q] * w[q];
      w[a] = s / A[a][a];
    }
    double ssum = 0.0;
    for (int a = 0; a < NC; a++) ssum += w[a];
    for (int a = 0; a < NC; a++) wi[a] = w[a] / ssum;
  }
  __syncthreads();

  double o = 0.0;
#pragma unroll
  for (int c = 0; c < NC; c++) o += wc[c][t] * wi[c];
  out[(size_t)j * NA + t] = (float)o;
}

extern "C" void kernel_launch(void* const* d_in, const int* in_sizes, int n_in,
                              void* d_out, int out_size, void* d_ws, size_t ws_size,
                              hipStream_t stream) {
  const float* cov  = (const float*)d_in[0];
  const float* rets = (const float*)d_in[1];
  float* out = (float*)d_out;
  char* ws = (char*)d_ws;

  const size_t g_bytes = (size_t)NS * NA * NA * sizeof(double);        // 32 MiB
  double* G          = (double*)(ws);
  double* inertiaAll = (double*)(ws + g_bytes);                        // 5 KiB
  int*    ixsAll     = (int*)   (ws + g_bytes + 5120);                 // 640 KiB
  double* wc_all     = (double*)(ws + g_bytes + 5120 + 655360);        // 1 MiB
  double* gbuf_all   = G;       // alias: G dead after kmeans

  hipLaunchKernelGGL(nco_gram_kernel,   dim3(NS * 10), dim3(NA),  0, stream, cov, G);
  hipLaunchKernelGGL(nco_kmeans_kernel, dim3(NS * NI), dim3(512), 0, stream,
                     G, ixsAll, inertiaAll);
  hipLaunchKernelGGL(nco_csolve_small,  dim3(NS * NC), dim3(NA),  0, stream,
                     cov, rets, ixsAll, inertiaAll, wc_all);
  hipLaunchKernelGGL(nco_csolve_large,  dim3(NS * NC), dim3(512), 0, stream,
                     cov, rets, ixsAll, inertiaAll, gbuf_all, wc_all);
  hipLaunchKernelGGL(nco_inter_kernel,  dim3(NS),      dim3(NA),  0, stream,
                     cov, rets, wc_all, out);
}